// Round 7
// baseline (189.287 us; speedup 1.0000x reference)
//
#include <hip/hip_runtime.h>
#include <math.h>

#define N_NODES 50000
#define N_EDGES 800000
#define NPART 8
#define PART_SZ ((N_NODES + NPART - 1) / NPART)   // 6250
#define CAP 64                                    // per-node bucket capacity
#define SCAT_BLOCKS 4096                          // 8 parts x 512 blocks
#define FC_BLOCKS 784                             // ceil(3125/4)=782, padded to x8
#define TILES (N_NODES / 16)                      // 3125 (exact)
#define NQ (N_EDGES / 4)                          // 200000 quads
#define NQH (NQ / 2)                              // 100000 quads per half

typedef __attribute__((ext_vector_type(8))) short short8;
typedef __attribute__((ext_vector_type(8))) unsigned short ushort8;
typedef __attribute__((ext_vector_type(4))) float v4f;
typedef __attribute__((ext_vector_type(2))) float v2f;
typedef __attribute__((ext_vector_type(4))) int int4v;

// ---- bf16 helpers (raw ushort storage) ----
__device__ __forceinline__ unsigned short f2bf(float f) {
    unsigned int u = __float_as_uint(f);
    u += 0x7fff + ((u >> 16) & 1);          // round-to-nearest-even
    return (unsigned short)(u >> 16);
}

// A-fragment load: lane supplies row m, k = kc*32 + quad*8 + j (j=0..7)
__device__ __forceinline__ short8 load_afrag(const float* X, size_t row, int K,
                                             int kc, int quad) {
    const float* p = X + row * K + kc * 32 + quad * 8;
    const float4 t0 = *(const float4*)p;
    const float4 t1 = *(const float4*)(p + 4);
    short8 a;
    a[0] = (short)f2bf(t0.x); a[1] = (short)f2bf(t0.y);
    a[2] = (short)f2bf(t0.z); a[3] = (short)f2bf(t0.w);
    a[4] = (short)f2bf(t1.x); a[5] = (short)f2bf(t1.y);
    a[6] = (short)f2bf(t1.z); a[7] = (short)f2bf(t1.w);
    return a;
}

// ---------------------------------------------------------------------------
// MFMA fc1 + attention-coefficient body (W staged into LDS as bf16).
// ---------------------------------------------------------------------------
template <int K, typename XT>
__device__ __forceinline__ void fc_att_body(
    const XT* __restrict__ X, const float* __restrict__ W,
    const float* __restrict__ al, const float* __restrict__ ar,
    unsigned short* __restrict__ Hout, float* __restrict__ el,
    float* __restrict__ er, int nTiles, int blk, unsigned short* Wlds)
{
    constexpr int KP = K + 8;                 // row pitch (u16): keeps 16B align
    constexpr int NKC = K / 32;
    const int tid = threadIdx.x;
    for (int i = tid; i < 64 * K; i += 256) {
        const int r = i / K, c = i - r * K;
        Wlds[r * KP + c] = f2bf(W[i]);
    }
    __syncthreads();

    const int lane = tid & 63;
    const int wave = tid >> 6;
    const int d = lane & 15;
    const int quad = lane >> 4;

    const int tile = blk * 4 + wave;
    if (tile >= nTiles) return;
    const int node0 = tile * 16;

    short8 wf[4][NKC];
#pragma unroll
    for (int ng = 0; ng < 4; ++ng) {
#pragma unroll
        for (int kc = 0; kc < NKC; ++kc) {
            wf[ng][kc] = *(const short8*)&Wlds[(ng * 16 + d) * KP + kc * 32 + quad * 8];
        }
    }

    v4f cc[4] = {{0.f,0.f,0.f,0.f},{0.f,0.f,0.f,0.f},{0.f,0.f,0.f,0.f},{0.f,0.f,0.f,0.f}};
#pragma unroll
    for (int kc = 0; kc < NKC; ++kc) {
        const short8 a = load_afrag(X, (size_t)(node0 + d), K, kc, quad);
        cc[0] = __builtin_amdgcn_mfma_f32_16x16x32_bf16(a, wf[0][kc], cc[0], 0, 0, 0);
        cc[1] = __builtin_amdgcn_mfma_f32_16x16x32_bf16(a, wf[1][kc], cc[1], 0, 0, 0);
        cc[2] = __builtin_amdgcn_mfma_f32_16x16x32_bf16(a, wf[2][kc], cc[2], 0, 0, 0);
        cc[3] = __builtin_amdgcn_mfma_f32_16x16x32_bf16(a, wf[3][kc], cc[3], 0, 0, 0);
    }

#pragma unroll
    for (int ng = 0; ng < 4; ++ng) {
        const float alv = al[ng * 16 + d];
        const float arv = ar[ng * 16 + d];
        const v4f c = cc[ng];
#pragma unroll
        for (int r = 0; r < 4; ++r) {
            const int node = node0 + quad * 4 + r;
            Hout[(size_t)node * 64 + ng * 16 + d] = f2bf(c[r]);
            float vel = c[r] * alv;
            float ver = c[r] * arv;
#pragma unroll
            for (int off = 1; off < 16; off <<= 1) {
                vel += __shfl_xor(vel, off);
                ver += __shfl_xor(ver, off);
            }
            if (d == 0) {
                el[node * 4 + ng] = vel;
                er[node * 4 + ng] = ver;
            }
        }
    }
}

// ---------------------------------------------------------------------------
// Scatter body over quad range [q0, q1): one quad (4 edges) per thread,
// batched atomics then batched stores. XCD partition = bid & 7.
// ---------------------------------------------------------------------------
__device__ __forceinline__ void scatter_half(
    int bid, const int* __restrict__ src, const int* __restrict__ dst,
    int* __restrict__ cnt16, unsigned short* __restrict__ col,
    int q0, int q1)
{
    const int part = bid & (NPART - 1);               // == XCD
    const int lo = part * PART_SZ;
    const int hi = lo + PART_SZ;
    const int tid_p = (bid >> 3) * 256 + (int)threadIdx.x;   // 0..131071
    const int q = q0 + tid_p;
    if (q >= q1) return;
    const int4v d4 = __builtin_nontemporal_load((const int4v*)dst + q);
    const int4v s4 = __builtin_nontemporal_load((const int4v*)src + q);
    const int dd[4] = {d4[0], d4[1], d4[2], d4[3]};
    const int ss[4] = {s4[0], s4[1], s4[2], s4[3]};
    int pos[4];
#pragma unroll
    for (int j = 0; j < 4; ++j) {
        pos[j] = -1;
        if (dd[j] >= lo && dd[j] < hi)
            pos[j] = atomicAdd(&cnt16[(unsigned)dd[j] * 16], 1);
    }
#pragma unroll
    for (int j = 0; j < 4; ++j) {
        if (pos[j] >= 0 && pos[j] < CAP)
            col[(unsigned)dd[j] * CAP + pos[j]] = (unsigned short)ss[j];
    }
}

// ---------------------------------------------------------------------------
// Layer-1 part A: blocks [0,FC_BLOCKS) run fc1 (MFMA); blocks
// [FC_BLOCKS,+SCAT_BLOCKS) scatter edge-half A. Part B (separate kernel)
// scatters edge-half B. Split is diagnostic-motivated: each scatter dispatch
// ~23-26us < agg durations, so the agg kernels surface in rocprof's top-5.
// Scatter is throughput-walled (R1), so the split costs only ~2us launch.
// ---------------------------------------------------------------------------
__global__ __launch_bounds__(256) void l1a_kernel(
    const float* __restrict__ X, const float* __restrict__ W,
    const float* __restrict__ al, const float* __restrict__ ar,
    unsigned short* __restrict__ Hout, float* __restrict__ el,
    float* __restrict__ er,
    const int* __restrict__ src, const int* __restrict__ dst,
    int* __restrict__ cnt16, unsigned short* __restrict__ col)
{
    __shared__ __align__(16) unsigned short Wlds[64 * (128 + 8)];
    if ((int)blockIdx.x < FC_BLOCKS) {
        fc_att_body<128, float>(X, W, al, ar, Hout, el, er,
                                TILES, (int)blockIdx.x, Wlds);
    } else {
        scatter_half((int)blockIdx.x - FC_BLOCKS, src, dst, cnt16, col,
                     0, NQH);
    }
}

__global__ __launch_bounds__(256) void l1b_kernel(
    const int* __restrict__ src, const int* __restrict__ dst,
    int* __restrict__ cnt16, unsigned short* __restrict__ col)
{
    scatter_half((int)blockIdx.x, src, dst, cnt16, col, NQH, NQ);
}

// ---------------------------------------------------------------------------
// One 16-edge aggregation step (R3 form -- best measured agg variant).
// ELS = element stride of el (4 for layer 1, 16 for layer 2's cnt16-pad view).
// ---------------------------------------------------------------------------
template <int ELS>
__device__ __forceinline__ void agg_iter16(
    const unsigned short* __restrict__ colrow, int i, int rm,
    const float* __restrict__ el, const unsigned int* __restrict__ Hf32,
    int hb, int hl, int j_a, unsigned h_a, int hd, float erv_a,
    float& accL0, float& accL1, float& accH0, float& accH1, float& sacc_a)
{
    const ushort8 sv0 = __builtin_nontemporal_load((const ushort8*)(colrow + i));
    const ushort8 sv1 = __builtin_nontemporal_load((const ushort8*)(colrow + i + 8));
    const unsigned sa0 = (unsigned)colrow[i + j_a];
    const unsigned sa1 = (unsigned)colrow[i + 8 + j_a];
    float x0 = el[sa0 * ELS + h_a] + erv_a;
    float x1 = el[sa1 * ELS + h_a] + erv_a;
    x0 = fmaxf(x0, 0.2f * x0);
    x1 = fmaxf(x1, 0.2f * x1);
    float a0 = __expf(x0);
    float a1 = __expf(x1);
    a0 = (j_a < rm) ? a0 : 0.f;
    a1 = (j_a + 8 < rm) ? a1 : 0.f;
    sacc_a += a0 + a1;
    unsigned uu[16];
#pragma unroll
    for (int j = 0; j < 8; ++j)
        uu[j] = Hf32[(unsigned)sv0[j] * 32u + (unsigned)hl];
#pragma unroll
    for (int j = 0; j < 8; ++j)
        uu[8 + j] = Hf32[(unsigned)sv1[j] * 32u + (unsigned)hl];
#pragma unroll
    for (int j = 0; j < 8; ++j) {
        const float aj = __shfl(a0, hb + j * 4 + hd);
        const float lo = __uint_as_float(uu[j] << 16);
        const float hi = __uint_as_float(uu[j] & 0xffff0000u);
        if (j & 1) { accL1 = fmaf(aj, lo, accL1); accH1 = fmaf(aj, hi, accH1); }
        else       { accL0 = fmaf(aj, lo, accL0); accH0 = fmaf(aj, hi, accH0); }
    }
#pragma unroll
    for (int j = 0; j < 8; ++j) {
        const float aj = __shfl(a1, hb + j * 4 + hd);
        const float lo = __uint_as_float(uu[8 + j] << 16);
        const float hi = __uint_as_float(uu[8 + j] & 0xffff0000u);
        if (j & 1) { accL1 = fmaf(aj, lo, accL1); accH1 = fmaf(aj, hi, accH1); }
        else       { accL0 = fmaf(aj, lo, accL0); accH0 = fmaf(aj, hi, accH0); }
    }
}

// Lane-pair agg walk, iteration-0 peeled (row 0 always safe: CAP rows exist,
// tail zeroed, rm-predication covers len<16).
template <int ELS>
__device__ __forceinline__ void agg_walk_pair(
    const unsigned short* __restrict__ colrow, int len, int len_max,
    const float* __restrict__ el, const unsigned int* __restrict__ Hf32,
    int hb, int hl, float erv_a,
    float& accL_out, float& accH_out, float& sacc_a_out)
{
    const int j_a = hl >> 2;
    const unsigned h_a = (unsigned)(hl & 3);
    const int hd = hl >> 3;
    float accL0 = 0.f, accL1 = 0.f, accH0 = 0.f, accH1 = 0.f;
    float sacc_a = 0.f;
    agg_iter16<ELS>(colrow, 0, len, el, Hf32, hb, hl, j_a, h_a, hd, erv_a,
                    accL0, accL1, accH0, accH1, sacc_a);
    for (int i = 16; i < len_max; i += 16)
        agg_iter16<ELS>(colrow, i, len - i, el, Hf32, hb, hl, j_a, h_a, hd,
                        erv_a, accL0, accL1, accH0, accH1, sacc_a);
    sacc_a += __shfl_xor(sacc_a, 4);
    sacc_a += __shfl_xor(sacc_a, 8);
    sacc_a += __shfl_xor(sacc_a, 16);
    sacc_a_out = sacc_a;
    accL_out = accL0 + accL1;
    accH_out = accH0 + accH1;
}

// ---------------------------------------------------------------------------
// FUSED layer-1 aggregation + fc2 (R3 form): one block = one 16-node tile.
// 8 waves x 2 nodes aggregate h1=relu(agg+b1) into a padded LDS tile
// ([16][33] u32), barrier, waves 0-3 each compute one head's 16x16 output
// tile (2 MFMAs) from LDS. h2 -> B buffer; el2/er2 -> cnt16 row padding.
// ---------------------------------------------------------------------------
__global__ __launch_bounds__(512) void agg1_fc2_fused(
    const int* __restrict__ cnt16, const unsigned short* __restrict__ col,
    const float* __restrict__ el1, const float* __restrict__ er1,
    const unsigned int* __restrict__ H1, const float* __restrict__ b1,
    const float* __restrict__ W2, const float* __restrict__ al2,
    const float* __restrict__ ar2,
    unsigned short* __restrict__ H2,
    float* __restrict__ el2, float* __restrict__ er2)   // stride-16 views
{
    __shared__ __align__(16) unsigned short W2lds[64 * 72];
    __shared__ __align__(16) unsigned int Hlds[16 * 33];

    const int tid = threadIdx.x;
    const int lane = tid & 63;
    const int wave = tid >> 6;
    const int hl = lane & 31;
    const int hb = lane & 32;
    const int nl = wave * 2 + (lane >> 5);            // 0..15 local node
    const int node = (int)blockIdx.x * 16 + nl;
    const int hd = hl >> 3;
    const int cg = hd * 16 + (hl & 7) * 2;

    // issue the latency-critical agg loads before W2 staging
    const int len = min(cnt16[(unsigned)node * 16], CAP);
    const float erv_a = er1[node * 4 + (hl & 3)];
    const float bL = b1[cg];
    const float bH = b1[cg + 1];

    // stage W2 -> bf16 LDS (4096 elems / 512 threads = 8 each)
    for (int i = tid; i < 64 * 64; i += 512) {
        const int r = i >> 6, c = i & 63;
        W2lds[r * 72 + c] = f2bf(W2[i]);
    }

    const int len_max = max(len, __shfl_xor(len, 32));
    float accL, accH, sacc_a;
    agg_walk_pair<4>(col + (unsigned)node * CAP, len, len_max, el1, H1,
                     hb, hl, erv_a, accL, accH, sacc_a);
    const float sc = __shfl(sacc_a, hb + hd);
    float vL = sc > 0.f ? accL / sc : 0.f;
    float vH = sc > 0.f ? accH / sc : 0.f;
    vL += bL;  vH += bH;
    vL = vL > 0.f ? vL : 0.f;
    vH = vH > 0.f ? vH : 0.f;
    // packed col pair (cg, cg+1) lands at u32-col cg/2 == hl: row-major tile
    Hlds[nl * 33 + hl] = (unsigned)f2bf(vL) | ((unsigned)f2bf(vH) << 16);
    __syncthreads();
    if (wave >= 4) return;

    // ---- fc2: wave ng computes out-cols ng*16..ng*16+15 of the tile ----
    const int ng = wave;
    const int d = lane & 15;
    const int quad = lane >> 4;
    const unsigned short* lds16 = (const unsigned short*)Hlds;   // pitch 66 u16
    const short8 wf0 = *(const short8*)&W2lds[(ng * 16 + d) * 72 + quad * 8];
    const short8 wf1 = *(const short8*)&W2lds[(ng * 16 + d) * 72 + 32 + quad * 8];
    const short8 a0 = *(const short8*)&lds16[(unsigned)d * 66 + quad * 8];
    const short8 a1 = *(const short8*)&lds16[(unsigned)d * 66 + 32 + quad * 8];
    v4f c0 = {0.f, 0.f, 0.f, 0.f};
    c0 = __builtin_amdgcn_mfma_f32_16x16x32_bf16(a0, wf0, c0, 0, 0, 0);
    c0 = __builtin_amdgcn_mfma_f32_16x16x32_bf16(a1, wf1, c0, 0, 0, 0);

    const float alv = al2[ng * 16 + d];
    const float arv = ar2[ng * 16 + d];
#pragma unroll
    for (int r = 0; r < 4; ++r) {
        const int node2 = (int)blockIdx.x * 16 + quad * 4 + r;
        H2[(size_t)node2 * 64 + ng * 16 + d] = f2bf(c0[r]);
        float vel = c0[r] * alv;
        float ver = c0[r] * arv;
#pragma unroll
        for (int off = 1; off < 16; off <<= 1) {
            vel += __shfl_xor(vel, off);
            ver += __shfl_xor(ver, off);
        }
        if (d == 0) {
            el2[node2 * 16 + ng] = vel;
            er2[node2 * 16 + ng] = ver;
        }
    }
}

// ---------------------------------------------------------------------------
// layer-2 aggregation (2 nodes/wave): head-mean (+b2) then 16-dim log-softmax.
// el2/er2 are the stride-16 cnt16-padding views.
// ---------------------------------------------------------------------------
__global__ __launch_bounds__(256) void agg_final_kernel(
    const int* __restrict__ cnt16, const unsigned short* __restrict__ col,
    const float* __restrict__ el2, const float* __restrict__ er2,
    const unsigned int* __restrict__ Hf32, const float* __restrict__ b,
    float* __restrict__ out, int n)
{
    const int lane = threadIdx.x & 63;
    const int wave = threadIdx.x >> 6;
    const int hl = lane & 31;
    const int hb = lane & 32;
    const int node = blockIdx.x * 8 + wave * 2 + (lane >> 5);
    if (node >= n) return;
    const int hd = hl >> 3;
    const int cg = hd * 16 + (hl & 7) * 2;
    const float erv_a = er2[node * 16 + (hl & 3)];
    const float bL = b[cg];
    const float bH = b[cg + 1];
    const int len = min(cnt16[(unsigned)node * 16], CAP);
    const int len_max = max(len, __shfl_xor(len, 32));
    float accL, accH, sacc_a;
    agg_walk_pair<16>(col + (unsigned)node * CAP, len, len_max, el2, Hf32,
                      hb, hl, erv_a, accL, accH, sacc_a);
    const float sc = __shfl(sacc_a, hb + hd);
    float zL = sc > 0.f ? accL / sc : 0.f;
    float zH = sc > 0.f ? accH / sc : 0.f;
    zL += bL;   zH += bH;
    zL += __shfl_xor(zL, 8);  zL += __shfl_xor(zL, 16);  zL *= 0.25f;
    zH += __shfl_xor(zH, 8);  zH += __shfl_xor(zH, 16);  zH *= 0.25f;
    float m = fmaxf(zL, zH);
    m = fmaxf(m, __shfl_xor(m, 1));
    m = fmaxf(m, __shfl_xor(m, 2));
    m = fmaxf(m, __shfl_xor(m, 4));
    float se = __expf(zL - m) + __expf(zH - m);
    se += __shfl_xor(se, 1);
    se += __shfl_xor(se, 2);
    se += __shfl_xor(se, 4);
    const float lse = __logf(se);
    if (hl < 8) {
        v2f r;
        r[0] = zL - m - lse;
        r[1] = zH - m - lse;
        __builtin_nontemporal_store(r, (v2f*)(out + (size_t)node * 16 + hl * 2));
    }
}

extern "C" void kernel_launch(void* const* d_in, const int* in_sizes, int n_in,
                              void* d_out, int out_size, void* d_ws, size_t ws_size,
                              hipStream_t stream)
{
    const float* feat = (const float*)d_in[0];
    const int*   src  = (const int*)d_in[1];
    const int*   dst  = (const int*)d_in[2];
    const float* W1   = (const float*)d_in[3];
    const float* al1  = (const float*)d_in[4];
    const float* ar1  = (const float*)d_in[5];
    const float* b1   = (const float*)d_in[6];
    const float* W2   = (const float*)d_in[7];
    const float* al2  = (const float*)d_in[8];
    const float* ar2  = (const float*)d_in[9];
    const float* b2   = (const float*)d_in[10];
    float* out = (float*)d_out;

    float* el1 = (float*)d_ws;                                // [N,4]
    float* er1 = el1 + N_NODES * 4;                           // [N,4]
    int*   cnt16 = (int*)(er1 + N_NODES * 4);                 // [N*16] padded
    uintptr_t p = ((uintptr_t)(cnt16 + N_NODES * 16) + 15) & ~(uintptr_t)15;
    unsigned short* col = (unsigned short*)p;                 // [N*CAP + 64]
    unsigned short* A   = col + (size_t)N_NODES * CAP + 64;   // h1 [N,64] bf16
    unsigned short* B   = A + (size_t)N_NODES * 64;           // h2 [N,64] bf16
    // layer-2 attention coeffs live in the cnt16 row padding (bytes 16..47
    // of each 64B row): zero workspace growth, disjoint from the counter.
    float* el2 = (float*)cnt16 + 4;                           // stride 16
    float* er2 = (float*)cnt16 + 8;                           // stride 16

    const int AB2 = (N_NODES + 7) / 8;              // 6250 agg blocks

    // ---- bucket-CSR zeroing (cnt16 rows incl. el2/er2 pads + col tail) ----
    (void)hipMemsetAsync(cnt16, 0, (size_t)((char*)A - (char*)cnt16), stream);

    // ---- layer 1: fc1 MFMA + scatter half A, then scatter half B ----
    l1a_kernel<<<FC_BLOCKS + SCAT_BLOCKS, 256, 0, stream>>>(
        feat, W1, al1, ar1, A, el1, er1, src, dst, cnt16, col);
    l1b_kernel<<<SCAT_BLOCKS, 256, 0, stream>>>(src, dst, cnt16, col);

    // ---- agg1 + fc2 fused (h1 never leaves the block) ----
    agg1_fc2_fused<<<TILES, 512, 0, stream>>>(
        cnt16, col, el1, er1, (const unsigned int*)A, b1,
        W2, al2, ar2, B, el2, er2);

    // ---- layer 2 aggregation + log-softmax ----
    agg_final_kernel<<<AB2, 256, 0, stream>>>(cnt16, col, el2, er2,
                                              (const unsigned int*)B, b2,
                                              out, N_NODES);
}

// Round 8
// 183.062 us; speedup vs baseline: 1.0340x; 1.0340x over previous
//
#include <hip/hip_runtime.h>
#include <math.h>

#define N_NODES 50000
#define N_EDGES 800000
#define NPART 8
#define PART_SZ ((N_NODES + NPART - 1) / NPART)   // 6250
#define CAP 64                                    // per-node bucket capacity
#define SCAT_BLOCKS 4096                          // 8 parts x 512 blocks
#define FC_BLOCKS 784                             // ceil(3125/4)=782, padded to x8
#define TILES (N_NODES / 16)                      // 3125 (exact)

typedef __attribute__((ext_vector_type(8))) short short8;
typedef __attribute__((ext_vector_type(8))) unsigned short ushort8;
typedef __attribute__((ext_vector_type(4))) float v4f;
typedef __attribute__((ext_vector_type(2))) float v2f;
typedef __attribute__((ext_vector_type(4))) int int4v;

// ---- bf16 helpers (raw ushort storage) ----
__device__ __forceinline__ unsigned short f2bf(float f) {
    unsigned int u = __float_as_uint(f);
    u += 0x7fff + ((u >> 16) & 1);          // round-to-nearest-even
    return (unsigned short)(u >> 16);
}

// A-fragment load: lane supplies row m, k = kc*32 + quad*8 + j (j=0..7)
__device__ __forceinline__ short8 load_afrag(const float* X, size_t row, int K,
                                             int kc, int quad) {
    const float* p = X + row * K + kc * 32 + quad * 8;
    const float4 t0 = *(const float4*)p;
    const float4 t1 = *(const float4*)(p + 4);
    short8 a;
    a[0] = (short)f2bf(t0.x); a[1] = (short)f2bf(t0.y);
    a[2] = (short)f2bf(t0.z); a[3] = (short)f2bf(t0.w);
    a[4] = (short)f2bf(t1.x); a[5] = (short)f2bf(t1.y);
    a[6] = (short)f2bf(t1.z); a[7] = (short)f2bf(t1.w);
    return a;
}

// ---------------------------------------------------------------------------
// MFMA fc1 + attention-coefficient body (W staged into LDS as bf16).
// ---------------------------------------------------------------------------
template <int K, typename XT>
__device__ __forceinline__ void fc_att_body(
    const XT* __restrict__ X, const float* __restrict__ W,
    const float* __restrict__ al, const float* __restrict__ ar,
    unsigned short* __restrict__ Hout, float* __restrict__ el,
    float* __restrict__ er, int nTiles, int blk, unsigned short* Wlds)
{
    constexpr int KP = K + 8;                 // row pitch (u16): keeps 16B align
    constexpr int NKC = K / 32;
    const int tid = threadIdx.x;
    for (int i = tid; i < 64 * K; i += 256) {
        const int r = i / K, c = i - r * K;
        Wlds[r * KP + c] = f2bf(W[i]);
    }
    __syncthreads();

    const int lane = tid & 63;
    const int wave = tid >> 6;
    const int d = lane & 15;
    const int quad = lane >> 4;

    const int tile = blk * 4 + wave;
    if (tile >= nTiles) return;
    const int node0 = tile * 16;

    short8 wf[4][NKC];
#pragma unroll
    for (int ng = 0; ng < 4; ++ng) {
#pragma unroll
        for (int kc = 0; kc < NKC; ++kc) {
            wf[ng][kc] = *(const short8*)&Wlds[(ng * 16 + d) * KP + kc * 32 + quad * 8];
        }
    }

    v4f cc[4] = {{0.f,0.f,0.f,0.f},{0.f,0.f,0.f,0.f},{0.f,0.f,0.f,0.f},{0.f,0.f,0.f,0.f}};
#pragma unroll
    for (int kc = 0; kc < NKC; ++kc) {
        const short8 a = load_afrag(X, (size_t)(node0 + d), K, kc, quad);
        cc[0] = __builtin_amdgcn_mfma_f32_16x16x32_bf16(a, wf[0][kc], cc[0], 0, 0, 0);
        cc[1] = __builtin_amdgcn_mfma_f32_16x16x32_bf16(a, wf[1][kc], cc[1], 0, 0, 0);
        cc[2] = __builtin_amdgcn_mfma_f32_16x16x32_bf16(a, wf[2][kc], cc[2], 0, 0, 0);
        cc[3] = __builtin_amdgcn_mfma_f32_16x16x32_bf16(a, wf[3][kc], cc[3], 0, 0, 0);
    }

#pragma unroll
    for (int ng = 0; ng < 4; ++ng) {
        const float alv = al[ng * 16 + d];
        const float arv = ar[ng * 16 + d];
        const v4f c = cc[ng];
#pragma unroll
        for (int r = 0; r < 4; ++r) {
            const int node = node0 + quad * 4 + r;
            Hout[(size_t)node * 64 + ng * 16 + d] = f2bf(c[r]);
            float vel = c[r] * alv;
            float ver = c[r] * arv;
#pragma unroll
            for (int off = 1; off < 16; off <<= 1) {
                vel += __shfl_xor(vel, off);
                ver += __shfl_xor(ver, off);
            }
            if (d == 0) {
                el[node * 4 + ng] = vel;
                er[node * 4 + ng] = ver;
            }
        }
    }
}

// ---------------------------------------------------------------------------
// Fused layer-1 launch: blocks [0,FC_BLOCKS) run fc1 (MFMA), blocks
// [FC_BLOCKS, FC_BLOCKS+SCAT_BLOCKS) run the bucket scatter (batched atomics).
// R1: scatter is transaction-THROUGHPUT bound; R7: splitting it costs ~10us.
// Single fused launch (R3 form) is the measured best.
// ---------------------------------------------------------------------------
__global__ __launch_bounds__(256) void l1_fused_kernel(
    const float* __restrict__ X, const float* __restrict__ W,
    const float* __restrict__ al, const float* __restrict__ ar,
    unsigned short* __restrict__ Hout, float* __restrict__ el,
    float* __restrict__ er,
    const int* __restrict__ src, const int* __restrict__ dst,
    int* __restrict__ cnt16, unsigned short* __restrict__ col)
{
    __shared__ __align__(16) unsigned short Wlds[64 * (128 + 8)];
    if ((int)blockIdx.x < FC_BLOCKS) {
        fc_att_body<128, float>(X, W, al, ar, Hout, el, er,
                                TILES, (int)blockIdx.x, Wlds);
    } else {
        const int bid = (int)blockIdx.x - FC_BLOCKS;
        const int part = bid & (NPART - 1);           // == blockIdx & 7 == XCD
        const int lo = part * PART_SZ;
        const int hi = lo + PART_SZ;
        const int tid_p = (bid >> 3) * 256 + (int)threadIdx.x;
        const int stride = (SCAT_BLOCKS / NPART) * 256;                // 131072
        const int4v* dst4 = (const int4v*)dst;
        const int4v* src4 = (const int4v*)src;
        const int NQ = N_EDGES / 4;                                    // 200000
        for (int q = tid_p; q < NQ; q += 2 * stride) {
            const int q2 = q + stride;
            const bool ok2 = q2 < NQ;
            const int4v dA = __builtin_nontemporal_load(dst4 + q);
            const int4v sA = __builtin_nontemporal_load(src4 + q);
            const int4v dB = ok2 ? __builtin_nontemporal_load(dst4 + q2) : (int4v){-1,-1,-1,-1};
            const int4v sB = ok2 ? __builtin_nontemporal_load(src4 + q2) : (int4v){0,0,0,0};
            const int dd[8] = {dA[0], dA[1], dA[2], dA[3], dB[0], dB[1], dB[2], dB[3]};
            const int ss[8] = {sA[0], sA[1], sA[2], sA[3], sB[0], sB[1], sB[2], sB[3]};
            int pos[8];
#pragma unroll
            for (int j = 0; j < 8; ++j) {
                pos[j] = -1;
                if (dd[j] >= lo && dd[j] < hi)
                    pos[j] = atomicAdd(&cnt16[(unsigned)dd[j] * 16], 1);
            }
#pragma unroll
            for (int j = 0; j < 8; ++j) {
                if (pos[j] >= 0 && pos[j] < CAP)
                    col[(unsigned)dd[j] * CAP + pos[j]] = (unsigned short)ss[j];
            }
        }
    }
}

// ---------------------------------------------------------------------------
// One 16-edge aggregation step. ELS = element stride of el (4 layer-1,
// 16 layer-2's cnt16-padding view).
// ---------------------------------------------------------------------------
template <int ELS>
__device__ __forceinline__ void agg_iter16(
    const unsigned short* __restrict__ colrow, int i, int rm,
    const float* __restrict__ el, const unsigned int* __restrict__ Hf32,
    int hb, int hl, int j_a, unsigned h_a, int hd, float erv_a,
    float& accL0, float& accL1, float& accH0, float& accH1, float& sacc_a)
{
    const ushort8 sv0 = __builtin_nontemporal_load((const ushort8*)(colrow + i));
    const ushort8 sv1 = __builtin_nontemporal_load((const ushort8*)(colrow + i + 8));
    const unsigned sa0 = (unsigned)colrow[i + j_a];
    const unsigned sa1 = (unsigned)colrow[i + 8 + j_a];
    float x0 = el[sa0 * ELS + h_a] + erv_a;
    float x1 = el[sa1 * ELS + h_a] + erv_a;
    x0 = fmaxf(x0, 0.2f * x0);
    x1 = fmaxf(x1, 0.2f * x1);
    float a0 = __expf(x0);
    float a1 = __expf(x1);
    a0 = (j_a < rm) ? a0 : 0.f;
    a1 = (j_a + 8 < rm) ? a1 : 0.f;
    sacc_a += a0 + a1;
    unsigned uu[16];
#pragma unroll
    for (int j = 0; j < 8; ++j)
        uu[j] = Hf32[(unsigned)sv0[j] * 32u + (unsigned)hl];
#pragma unroll
    for (int j = 0; j < 8; ++j)
        uu[8 + j] = Hf32[(unsigned)sv1[j] * 32u + (unsigned)hl];
#pragma unroll
    for (int j = 0; j < 8; ++j) {
        const float aj = __shfl(a0, hb + j * 4 + hd);
        const float lo = __uint_as_float(uu[j] << 16);
        const float hi = __uint_as_float(uu[j] & 0xffff0000u);
        if (j & 1) { accL1 = fmaf(aj, lo, accL1); accH1 = fmaf(aj, hi, accH1); }
        else       { accL0 = fmaf(aj, lo, accL0); accH0 = fmaf(aj, hi, accH0); }
    }
#pragma unroll
    for (int j = 0; j < 8; ++j) {
        const float aj = __shfl(a1, hb + j * 4 + hd);
        const float lo = __uint_as_float(uu[8 + j] << 16);
        const float hi = __uint_as_float(uu[8 + j] & 0xffff0000u);
        if (j & 1) { accL1 = fmaf(aj, lo, accL1); accH1 = fmaf(aj, hi, accH1); }
        else       { accL0 = fmaf(aj, lo, accL0); accH0 = fmaf(aj, hi, accH0); }
    }
}

// Fixed-trip unrolled walk body: NIT compile-time iterations. All colrow/el
// load addresses are static offsets from the base, so the scheduler can hoist
// every independent load and overlap iter i+1's gathers with iter i's FMAs.
template <int ELS, int NIT>
__device__ __forceinline__ void agg_walk_fixed(
    const unsigned short* __restrict__ colrow, int len,
    const float* __restrict__ el, const unsigned int* __restrict__ Hf32,
    int hb, int hl, int j_a, unsigned h_a, int hd, float erv_a,
    float& accL0, float& accL1, float& accH0, float& accH1, float& sacc_a)
{
#pragma unroll
    for (int t = 0; t < NIT; ++t)
        agg_iter16<ELS>(colrow, t * 16, len - t * 16, el, Hf32, hb, hl,
                        j_a, h_a, hd, erv_a, accL0, accL1, accH0, accH1,
                        sacc_a);
}

// Lane-pair agg walk: wave-uniform switch into 1/2/3/4-trip unrolled bodies
// (len_max <= CAP = 64 -> at most 4). Rows always exist (CAP alloc), tail
// zeroed, rm-predication zeroes out-of-range alphas -- so every variant is
// safe for any len in its class.
template <int ELS>
__device__ __forceinline__ void agg_walk_pair(
    const unsigned short* __restrict__ colrow, int len, int len_max,
    const float* __restrict__ el, const unsigned int* __restrict__ Hf32,
    int hb, int hl, float erv_a,
    float& accL_out, float& accH_out, float& sacc_a_out)
{
    const int j_a = hl >> 2;
    const unsigned h_a = (unsigned)(hl & 3);
    const int hd = hl >> 3;
    float accL0 = 0.f, accL1 = 0.f, accH0 = 0.f, accH1 = 0.f;
    float sacc_a = 0.f;
    const int nit = (len_max + 15) >> 4;     // 0..4, wave-uniform
    switch (nit) {
    case 0:
    case 1:
        agg_walk_fixed<ELS, 1>(colrow, len, el, Hf32, hb, hl, j_a, h_a, hd,
                               erv_a, accL0, accL1, accH0, accH1, sacc_a);
        break;
    case 2:
        agg_walk_fixed<ELS, 2>(colrow, len, el, Hf32, hb, hl, j_a, h_a, hd,
                               erv_a, accL0, accL1, accH0, accH1, sacc_a);
        break;
    case 3:
        agg_walk_fixed<ELS, 3>(colrow, len, el, Hf32, hb, hl, j_a, h_a, hd,
                               erv_a, accL0, accL1, accH0, accH1, sacc_a);
        break;
    default:
        agg_walk_fixed<ELS, 4>(colrow, len, el, Hf32, hb, hl, j_a, h_a, hd,
                               erv_a, accL0, accL1, accH0, accH1, sacc_a);
        break;
    }
    sacc_a += __shfl_xor(sacc_a, 4);
    sacc_a += __shfl_xor(sacc_a, 8);
    sacc_a += __shfl_xor(sacc_a, 16);
    sacc_a_out = sacc_a;
    accL_out = accL0 + accL1;
    accH_out = accH0 + accH1;
}

// ---------------------------------------------------------------------------
// FUSED layer-1 aggregation + fc2 (R3 form): one block = one 16-node tile.
// 8 waves x 2 nodes aggregate h1=relu(agg+b1) into a padded LDS tile
// ([16][33] u32), barrier, waves 0-3 each compute one head's 16x16 output
// tile (2 MFMAs) from LDS. h2 -> B buffer; el2/er2 -> cnt16 row padding.
// ---------------------------------------------------------------------------
__global__ __launch_bounds__(512) void agg1_fc2_fused(
    const int* __restrict__ cnt16, const unsigned short* __restrict__ col,
    const float* __restrict__ el1, const float* __restrict__ er1,
    const unsigned int* __restrict__ H1, const float* __restrict__ b1,
    const float* __restrict__ W2, const float* __restrict__ al2,
    const float* __restrict__ ar2,
    unsigned short* __restrict__ H2,
    float* __restrict__ el2, float* __restrict__ er2)   // stride-16 views
{
    __shared__ __align__(16) unsigned short W2lds[64 * 72];
    __shared__ __align__(16) unsigned int Hlds[16 * 33];

    const int tid = threadIdx.x;
    const int lane = tid & 63;
    const int wave = tid >> 6;
    const int hl = lane & 31;
    const int hb = lane & 32;
    const int nl = wave * 2 + (lane >> 5);            // 0..15 local node
    const int node = (int)blockIdx.x * 16 + nl;
    const int hd = hl >> 3;
    const int cg = hd * 16 + (hl & 7) * 2;

    // issue the latency-critical agg loads before W2 staging
    const int len = min(cnt16[(unsigned)node * 16], CAP);
    const float erv_a = er1[node * 4 + (hl & 3)];
    const float bL = b1[cg];
    const float bH = b1[cg + 1];

    // stage W2 -> bf16 LDS (4096 elems / 512 threads = 8 each)
    for (int i = tid; i < 64 * 64; i += 512) {
        const int r = i >> 6, c = i & 63;
        W2lds[r * 72 + c] = f2bf(W2[i]);
    }

    const int len_max = max(len, __shfl_xor(len, 32));
    float accL, accH, sacc_a;
    agg_walk_pair<4>(col + (unsigned)node * CAP, len, len_max, el1, H1,
                     hb, hl, erv_a, accL, accH, sacc_a);
    const float sc = __shfl(sacc_a, hb + hd);
    float vL = sc > 0.f ? accL / sc : 0.f;
    float vH = sc > 0.f ? accH / sc : 0.f;
    vL += bL;  vH += bH;
    vL = vL > 0.f ? vL : 0.f;
    vH = vH > 0.f ? vH : 0.f;
    // packed col pair (cg, cg+1) lands at u32-col cg/2 == hl: row-major tile
    Hlds[nl * 33 + hl] = (unsigned)f2bf(vL) | ((unsigned)f2bf(vH) << 16);
    __syncthreads();
    if (wave >= 4) return;

    // ---- fc2: wave ng computes out-cols ng*16..ng*16+15 of the tile ----
    const int ng = wave;
    const int d = lane & 15;
    const int quad = lane >> 4;
    const unsigned short* lds16 = (const unsigned short*)Hlds;   // pitch 66 u16
    const short8 wf0 = *(const short8*)&W2lds[(ng * 16 + d) * 72 + quad * 8];
    const short8 wf1 = *(const short8*)&W2lds[(ng * 16 + d) * 72 + 32 + quad * 8];
    const short8 a0 = *(const short8*)&lds16[(unsigned)d * 66 + quad * 8];
    const short8 a1 = *(const short8*)&lds16[(unsigned)d * 66 + 32 + quad * 8];
    v4f c0 = {0.f, 0.f, 0.f, 0.f};
    c0 = __builtin_amdgcn_mfma_f32_16x16x32_bf16(a0, wf0, c0, 0, 0, 0);
    c0 = __builtin_amdgcn_mfma_f32_16x16x32_bf16(a1, wf1, c0, 0, 0, 0);

    const float alv = al2[ng * 16 + d];
    const float arv = ar2[ng * 16 + d];
#pragma unroll
    for (int r = 0; r < 4; ++r) {
        const int node2 = (int)blockIdx.x * 16 + quad * 4 + r;
        H2[(size_t)node2 * 64 + ng * 16 + d] = f2bf(c0[r]);
        float vel = c0[r] * alv;
        float ver = c0[r] * arv;
#pragma unroll
        for (int off = 1; off < 16; off <<= 1) {
            vel += __shfl_xor(vel, off);
            ver += __shfl_xor(ver, off);
        }
        if (d == 0) {
            el2[node2 * 16 + ng] = vel;
            er2[node2 * 16 + ng] = ver;
        }
    }
}

// ---------------------------------------------------------------------------
// layer-2 aggregation (2 nodes/wave): head-mean (+b2) then 16-dim log-softmax.
// el2/er2 are the stride-16 cnt16-padding views.
// ---------------------------------------------------------------------------
__global__ __launch_bounds__(256) void agg_final_kernel(
    const int* __restrict__ cnt16, const unsigned short* __restrict__ col,
    const float* __restrict__ el2, const float* __restrict__ er2,
    const unsigned int* __restrict__ Hf32, const float* __restrict__ b,
    float* __restrict__ out, int n)
{
    const int lane = threadIdx.x & 63;
    const int wave = threadIdx.x >> 6;
    const int hl = lane & 31;
    const int hb = lane & 32;
    const int node = blockIdx.x * 8 + wave * 2 + (lane >> 5);
    if (node >= n) return;
    const int hd = hl >> 3;
    const int cg = hd * 16 + (hl & 7) * 2;
    const float erv_a = er2[node * 16 + (hl & 3)];
    const float bL = b[cg];
    const float bH = b[cg + 1];
    const int len = min(cnt16[(unsigned)node * 16], CAP);
    const int len_max = max(len, __shfl_xor(len, 32));
    float accL, accH, sacc_a;
    agg_walk_pair<16>(col + (unsigned)node * CAP, len, len_max, el2, Hf32,
                      hb, hl, erv_a, accL, accH, sacc_a);
    const float sc = __shfl(sacc_a, hb + hd);
    float zL = sc > 0.f ? accL / sc : 0.f;
    float zH = sc > 0.f ? accH / sc : 0.f;
    zL += bL;   zH += bH;
    zL += __shfl_xor(zL, 8);  zL += __shfl_xor(zL, 16);  zL *= 0.25f;
    zH += __shfl_xor(zH, 8);  zH += __shfl_xor(zH, 16);  zH *= 0.25f;
    float m = fmaxf(zL, zH);
    m = fmaxf(m, __shfl_xor(m, 1));
    m = fmaxf(m, __shfl_xor(m, 2));
    m = fmaxf(m, __shfl_xor(m, 4));
    float se = __expf(zL - m) + __expf(zH - m);
    se += __shfl_xor(se, 1);
    se += __shfl_xor(se, 2);
    se += __shfl_xor(se, 4);
    const float lse = __logf(se);
    if (hl < 8) {
        v2f r;
        r[0] = zL - m - lse;
        r[1] = zH - m - lse;
        __builtin_nontemporal_store(r, (v2f*)(out + (size_t)node * 16 + hl * 2));
    }
}

extern "C" void kernel_launch(void* const* d_in, const int* in_sizes, int n_in,
                              void* d_out, int out_size, void* d_ws, size_t ws_size,
                              hipStream_t stream)
{
    const float* feat = (const float*)d_in[0];
    const int*   src  = (const int*)d_in[1];
    const int*   dst  = (const int*)d_in[2];
    const float* W1   = (const float*)d_in[3];
    const float* al1  = (const float*)d_in[4];
    const float* ar1  = (const float*)d_in[5];
    const float* b1   = (const float*)d_in[6];
    const float* W2   = (const float*)d_in[7];
    const float* al2  = (const float*)d_in[8];
    const float* ar2  = (const float*)d_in[9];
    const float* b2   = (const float*)d_in[10];
    float* out = (float*)d_out;

    float* el1 = (float*)d_ws;                                // [N,4]
    float* er1 = el1 + N_NODES * 4;                           // [N,4]
    int*   cnt16 = (int*)(er1 + N_NODES * 4);                 // [N*16] padded
    uintptr_t p = ((uintptr_t)(cnt16 + N_NODES * 16) + 15) & ~(uintptr_t)15;
    unsigned short* col = (unsigned short*)p;                 // [N*CAP + 64]
    unsigned short* A   = col + (size_t)N_NODES * CAP + 64;   // h1 [N,64] bf16
    unsigned short* B   = A + (size_t)N_NODES * 64;           // h2 [N,64] bf16
    // layer-2 attention coeffs live in the cnt16 row padding (bytes 16..47
    // of each 64B row): zero workspace growth, disjoint from the counter.
    float* el2 = (float*)cnt16 + 4;                           // stride 16
    float* er2 = (float*)cnt16 + 8;                           // stride 16

    const int AB2 = (N_NODES + 7) / 8;              // 6250 agg blocks

    // ---- bucket-CSR zeroing (cnt16 rows incl. el2/er2 pads + col tail) ----
    (void)hipMemsetAsync(cnt16, 0, (size_t)((char*)A - (char*)cnt16), stream);

    // ---- layer 1: fc1 MFMA overlapped with bucket scatter (independent) ----
    l1_fused_kernel<<<FC_BLOCKS + SCAT_BLOCKS, 256, 0, stream>>>(
        feat, W1, al1, ar1, A, el1, er1, src, dst, cnt16, col);

    // ---- agg1 + fc2 fused (h1 never leaves the block) ----
    agg1_fc2_fused<<<TILES, 512, 0, stream>>>(
        cnt16, col, el1, er1, (const unsigned int*)A, b1,
        W2, al2, ar2, B, el2, er2);

    // ---- layer 2 aggregation + log-softmax ----
    agg_final_kernel<<<AB2, 256, 0, stream>>>(cnt16, col, el2, er2,
                                              (const unsigned int*)B, b2,
                                              out, N_NODES);
}

// Round 9
// 177.974 us; speedup vs baseline: 1.0636x; 1.0286x over previous
//
#include <hip/hip_runtime.h>
#include <math.h>

#define N_NODES 50000
#define N_EDGES 800000
#define NPART 8
#define PART_SZ ((N_NODES + NPART - 1) / NPART)   // 6250
#define CAP 64                                    // per-node bucket capacity
#define SCAT_BLOCKS 4096                          // 8 parts x 512 blocks
#define FC_BLOCKS 784                             // ceil(3125/4)=782, padded to x8
#define TILES (N_NODES / 16)                      // 3125 (exact)

typedef __attribute__((ext_vector_type(8))) short short8;
typedef __attribute__((ext_vector_type(8))) unsigned short ushort8;
typedef __attribute__((ext_vector_type(4))) float v4f;
typedef __attribute__((ext_vector_type(2))) float v2f;
typedef __attribute__((ext_vector_type(4))) int int4v;

// ---- bf16 helpers (raw ushort storage) ----
__device__ __forceinline__ unsigned short f2bf(float f) {
    unsigned int u = __float_as_uint(f);
    u += 0x7fff + ((u >> 16) & 1);          // round-to-nearest-even
    return (unsigned short)(u >> 16);
}

// A-fragment load: lane supplies row m, k = kc*32 + quad*8 + j (j=0..7)
__device__ __forceinline__ short8 load_afrag(const float* X, size_t row, int K,
                                             int kc, int quad) {
    const float* p = X + row * K + kc * 32 + quad * 8;
    const float4 t0 = *(const float4*)p;
    const float4 t1 = *(const float4*)(p + 4);
    short8 a;
    a[0] = (short)f2bf(t0.x); a[1] = (short)f2bf(t0.y);
    a[2] = (short)f2bf(t0.z); a[3] = (short)f2bf(t0.w);
    a[4] = (short)f2bf(t1.x); a[5] = (short)f2bf(t1.y);
    a[6] = (short)f2bf(t1.z); a[7] = (short)f2bf(t1.w);
    return a;
}

// ---------------------------------------------------------------------------
// MFMA fc1 + attention-coefficient body (W staged into LDS as bf16).
// ---------------------------------------------------------------------------
template <int K, typename XT>
__device__ __forceinline__ void fc_att_body(
    const XT* __restrict__ X, const float* __restrict__ W,
    const float* __restrict__ al, const float* __restrict__ ar,
    unsigned short* __restrict__ Hout, float* __restrict__ el,
    float* __restrict__ er, int nTiles, int blk, unsigned short* Wlds)
{
    constexpr int KP = K + 8;                 // row pitch (u16): keeps 16B align
    constexpr int NKC = K / 32;
    const int tid = threadIdx.x;
    for (int i = tid; i < 64 * K; i += 256) {
        const int r = i / K, c = i - r * K;
        Wlds[r * KP + c] = f2bf(W[i]);
    }
    __syncthreads();

    const int lane = tid & 63;
    const int wave = tid >> 6;
    const int d = lane & 15;
    const int quad = lane >> 4;

    const int tile = blk * 4 + wave;
    if (tile >= nTiles) return;
    const int node0 = tile * 16;

    short8 wf[4][NKC];
#pragma unroll
    for (int ng = 0; ng < 4; ++ng) {
#pragma unroll
        for (int kc = 0; kc < NKC; ++kc) {
            wf[ng][kc] = *(const short8*)&Wlds[(ng * 16 + d) * KP + kc * 32 + quad * 8];
        }
    }

    v4f cc[4] = {{0.f,0.f,0.f,0.f},{0.f,0.f,0.f,0.f},{0.f,0.f,0.f,0.f},{0.f,0.f,0.f,0.f}};
#pragma unroll
    for (int kc = 0; kc < NKC; ++kc) {
        const short8 a = load_afrag(X, (size_t)(node0 + d), K, kc, quad);
        cc[0] = __builtin_amdgcn_mfma_f32_16x16x32_bf16(a, wf[0][kc], cc[0], 0, 0, 0);
        cc[1] = __builtin_amdgcn_mfma_f32_16x16x32_bf16(a, wf[1][kc], cc[1], 0, 0, 0);
        cc[2] = __builtin_amdgcn_mfma_f32_16x16x32_bf16(a, wf[2][kc], cc[2], 0, 0, 0);
        cc[3] = __builtin_amdgcn_mfma_f32_16x16x32_bf16(a, wf[3][kc], cc[3], 0, 0, 0);
    }

#pragma unroll
    for (int ng = 0; ng < 4; ++ng) {
        const float alv = al[ng * 16 + d];
        const float arv = ar[ng * 16 + d];
        const v4f c = cc[ng];
#pragma unroll
        for (int r = 0; r < 4; ++r) {
            const int node = node0 + quad * 4 + r;
            Hout[(size_t)node * 64 + ng * 16 + d] = f2bf(c[r]);
            float vel = c[r] * alv;
            float ver = c[r] * arv;
#pragma unroll
            for (int off = 1; off < 16; off <<= 1) {
                vel += __shfl_xor(vel, off);
                ver += __shfl_xor(ver, off);
            }
            if (d == 0) {
                el[node * 4 + ng] = vel;
                er[node * 4 + ng] = ver;
            }
        }
    }
}

// ---------------------------------------------------------------------------
// Fused layer-1 launch: blocks [0,FC_BLOCKS) run fc1 (MFMA), blocks
// [FC_BLOCKS, FC_BLOCKS+SCAT_BLOCKS) run the bucket scatter (batched atomics).
// R1: scatter is transaction-THROUGHPUT bound; R7: splitting it costs ~10us.
// Single fused launch (R3 form) is the measured best.
// ---------------------------------------------------------------------------
__global__ __launch_bounds__(256) void l1_fused_kernel(
    const float* __restrict__ X, const float* __restrict__ W,
    const float* __restrict__ al, const float* __restrict__ ar,
    unsigned short* __restrict__ Hout, float* __restrict__ el,
    float* __restrict__ er,
    const int* __restrict__ src, const int* __restrict__ dst,
    int* __restrict__ cnt16, unsigned short* __restrict__ col)
{
    __shared__ __align__(16) unsigned short Wlds[64 * (128 + 8)];
    if ((int)blockIdx.x < FC_BLOCKS) {
        fc_att_body<128, float>(X, W, al, ar, Hout, el, er,
                                TILES, (int)blockIdx.x, Wlds);
    } else {
        const int bid = (int)blockIdx.x - FC_BLOCKS;
        const int part = bid & (NPART - 1);           // == blockIdx & 7 == XCD
        const int lo = part * PART_SZ;
        const int hi = lo + PART_SZ;
        const int tid_p = (bid >> 3) * 256 + (int)threadIdx.x;
        const int stride = (SCAT_BLOCKS / NPART) * 256;                // 131072
        const int4v* dst4 = (const int4v*)dst;
        const int4v* src4 = (const int4v*)src;
        const int NQ = N_EDGES / 4;                                    // 200000
        for (int q = tid_p; q < NQ; q += 2 * stride) {
            const int q2 = q + stride;
            const bool ok2 = q2 < NQ;
            const int4v dA = __builtin_nontemporal_load(dst4 + q);
            const int4v sA = __builtin_nontemporal_load(src4 + q);
            const int4v dB = ok2 ? __builtin_nontemporal_load(dst4 + q2) : (int4v){-1,-1,-1,-1};
            const int4v sB = ok2 ? __builtin_nontemporal_load(src4 + q2) : (int4v){0,0,0,0};
            const int dd[8] = {dA[0], dA[1], dA[2], dA[3], dB[0], dB[1], dB[2], dB[3]};
            const int ss[8] = {sA[0], sA[1], sA[2], sA[3], sB[0], sB[1], sB[2], sB[3]};
            int pos[8];
#pragma unroll
            for (int j = 0; j < 8; ++j) {
                pos[j] = -1;
                if (dd[j] >= lo && dd[j] < hi)
                    pos[j] = atomicAdd(&cnt16[(unsigned)dd[j] * 16], 1);
            }
#pragma unroll
            for (int j = 0; j < 8; ++j) {
                if (pos[j] >= 0 && pos[j] < CAP)
                    col[(unsigned)dd[j] * CAP + pos[j]] = (unsigned short)ss[j];
            }
        }
    }
}

// ---------------------------------------------------------------------------
// One 16-edge aggregation step (R3 form -- the measured-best agg variant;
// pipeline/perm/unroll/split all regressed, R5-R8). ELS = el stride (4 both
// layers now that el2/er2 are compact [N,4]).
// ---------------------------------------------------------------------------
template <int ELS>
__device__ __forceinline__ void agg_iter16(
    const unsigned short* __restrict__ colrow, int i, int rm,
    const float* __restrict__ el, const unsigned int* __restrict__ Hf32,
    int hb, int hl, int j_a, unsigned h_a, int hd, float erv_a,
    float& accL0, float& accL1, float& accH0, float& accH1, float& sacc_a)
{
    const ushort8 sv0 = __builtin_nontemporal_load((const ushort8*)(colrow + i));
    const ushort8 sv1 = __builtin_nontemporal_load((const ushort8*)(colrow + i + 8));
    const unsigned sa0 = (unsigned)colrow[i + j_a];
    const unsigned sa1 = (unsigned)colrow[i + 8 + j_a];
    float x0 = el[sa0 * ELS + h_a] + erv_a;
    float x1 = el[sa1 * ELS + h_a] + erv_a;
    x0 = fmaxf(x0, 0.2f * x0);
    x1 = fmaxf(x1, 0.2f * x1);
    float a0 = __expf(x0);
    float a1 = __expf(x1);
    a0 = (j_a < rm) ? a0 : 0.f;
    a1 = (j_a + 8 < rm) ? a1 : 0.f;
    sacc_a += a0 + a1;
    unsigned uu[16];
#pragma unroll
    for (int j = 0; j < 8; ++j)
        uu[j] = Hf32[(unsigned)sv0[j] * 32u + (unsigned)hl];
#pragma unroll
    for (int j = 0; j < 8; ++j)
        uu[8 + j] = Hf32[(unsigned)sv1[j] * 32u + (unsigned)hl];
#pragma unroll
    for (int j = 0; j < 8; ++j) {
        const float aj = __shfl(a0, hb + j * 4 + hd);
        const float lo = __uint_as_float(uu[j] << 16);
        const float hi = __uint_as_float(uu[j] & 0xffff0000u);
        if (j & 1) { accL1 = fmaf(aj, lo, accL1); accH1 = fmaf(aj, hi, accH1); }
        else       { accL0 = fmaf(aj, lo, accL0); accH0 = fmaf(aj, hi, accH0); }
    }
#pragma unroll
    for (int j = 0; j < 8; ++j) {
        const float aj = __shfl(a1, hb + j * 4 + hd);
        const float lo = __uint_as_float(uu[8 + j] << 16);
        const float hi = __uint_as_float(uu[8 + j] & 0xffff0000u);
        if (j & 1) { accL1 = fmaf(aj, lo, accL1); accH1 = fmaf(aj, hi, accH1); }
        else       { accL0 = fmaf(aj, lo, accL0); accH0 = fmaf(aj, hi, accH0); }
    }
}

// Lane-pair agg walk, iteration-0 peeled (row 0 always safe: CAP rows exist,
// tail zeroed, rm-predication covers len<16).
template <int ELS>
__device__ __forceinline__ void agg_walk_pair(
    const unsigned short* __restrict__ colrow, int len, int len_max,
    const float* __restrict__ el, const unsigned int* __restrict__ Hf32,
    int hb, int hl, float erv_a,
    float& accL_out, float& accH_out, float& sacc_a_out)
{
    const int j_a = hl >> 2;
    const unsigned h_a = (unsigned)(hl & 3);
    const int hd = hl >> 3;
    float accL0 = 0.f, accL1 = 0.f, accH0 = 0.f, accH1 = 0.f;
    float sacc_a = 0.f;
    agg_iter16<ELS>(colrow, 0, len, el, Hf32, hb, hl, j_a, h_a, hd, erv_a,
                    accL0, accL1, accH0, accH1, sacc_a);
    for (int i = 16; i < len_max; i += 16)
        agg_iter16<ELS>(colrow, i, len - i, el, Hf32, hb, hl, j_a, h_a, hd,
                        erv_a, accL0, accL1, accH0, accH1, sacc_a);
    sacc_a += __shfl_xor(sacc_a, 4);
    sacc_a += __shfl_xor(sacc_a, 8);
    sacc_a += __shfl_xor(sacc_a, 16);
    sacc_a_out = sacc_a;
    accL_out = accL0 + accL1;
    accH_out = accH0 + accH1;
}

// ---------------------------------------------------------------------------
// FUSED layer-1 aggregation + fc2 (R3 form): one block = one 16-node tile.
// 8 waves x 2 nodes aggregate h1=relu(agg+b1) into a padded LDS tile
// ([16][33] u32), barrier, waves 0-3 each compute one head's 16x16 output
// tile (2 MFMAs) from LDS. h2 -> B buffer; el2/er2 -> compact [N,4] arrays
// (was: stride-16 cnt16-padding -- 64B-strided el2 gathers touched ~8 lines
// per instr in agg_final; compact [N,4] matches layer 1's coalescing).
// ---------------------------------------------------------------------------
__global__ __launch_bounds__(512) void agg1_fc2_fused(
    const int* __restrict__ cnt16, const unsigned short* __restrict__ col,
    const float* __restrict__ el1, const float* __restrict__ er1,
    const unsigned int* __restrict__ H1, const float* __restrict__ b1,
    const float* __restrict__ W2, const float* __restrict__ al2,
    const float* __restrict__ ar2,
    unsigned short* __restrict__ H2,
    float* __restrict__ el2, float* __restrict__ er2)   // [N,4] compact
{
    __shared__ __align__(16) unsigned short W2lds[64 * 72];
    __shared__ __align__(16) unsigned int Hlds[16 * 33];

    const int tid = threadIdx.x;
    const int lane = tid & 63;
    const int wave = tid >> 6;
    const int hl = lane & 31;
    const int hb = lane & 32;
    const int nl = wave * 2 + (lane >> 5);            // 0..15 local node
    const int node = (int)blockIdx.x * 16 + nl;
    const int hd = hl >> 3;
    const int cg = hd * 16 + (hl & 7) * 2;

    // issue the latency-critical agg loads before W2 staging
    const int len = min(cnt16[(unsigned)node * 16], CAP);
    const float erv_a = er1[node * 4 + (hl & 3)];
    const float bL = b1[cg];
    const float bH = b1[cg + 1];

    // stage W2 -> bf16 LDS (4096 elems / 512 threads = 8 each)
    for (int i = tid; i < 64 * 64; i += 512) {
        const int r = i >> 6, c = i & 63;
        W2lds[r * 72 + c] = f2bf(W2[i]);
    }

    const int len_max = max(len, __shfl_xor(len, 32));
    float accL, accH, sacc_a;
    agg_walk_pair<4>(col + (unsigned)node * CAP, len, len_max, el1, H1,
                     hb, hl, erv_a, accL, accH, sacc_a);
    const float sc = __shfl(sacc_a, hb + hd);
    float vL = sc > 0.f ? accL / sc : 0.f;
    float vH = sc > 0.f ? accH / sc : 0.f;
    vL += bL;  vH += bH;
    vL = vL > 0.f ? vL : 0.f;
    vH = vH > 0.f ? vH : 0.f;
    // packed col pair (cg, cg+1) lands at u32-col cg/2 == hl: row-major tile
    Hlds[nl * 33 + hl] = (unsigned)f2bf(vL) | ((unsigned)f2bf(vH) << 16);
    __syncthreads();
    if (wave >= 4) return;

    // ---- fc2: wave ng computes out-cols ng*16..ng*16+15 of the tile ----
    const int ng = wave;
    const int d = lane & 15;
    const int quad = lane >> 4;
    const unsigned short* lds16 = (const unsigned short*)Hlds;   // pitch 66 u16
    const short8 wf0 = *(const short8*)&W2lds[(ng * 16 + d) * 72 + quad * 8];
    const short8 wf1 = *(const short8*)&W2lds[(ng * 16 + d) * 72 + 32 + quad * 8];
    const short8 a0 = *(const short8*)&lds16[(unsigned)d * 66 + quad * 8];
    const short8 a1 = *(const short8*)&lds16[(unsigned)d * 66 + 32 + quad * 8];
    v4f c0 = {0.f, 0.f, 0.f, 0.f};
    c0 = __builtin_amdgcn_mfma_f32_16x16x32_bf16(a0, wf0, c0, 0, 0, 0);
    c0 = __builtin_amdgcn_mfma_f32_16x16x32_bf16(a1, wf1, c0, 0, 0, 0);

    const float alv = al2[ng * 16 + d];
    const float arv = ar2[ng * 16 + d];
#pragma unroll
    for (int r = 0; r < 4; ++r) {
        const int node2 = (int)blockIdx.x * 16 + quad * 4 + r;
        H2[(size_t)node2 * 64 + ng * 16 + d] = f2bf(c0[r]);
        float vel = c0[r] * alv;
        float ver = c0[r] * arv;
#pragma unroll
        for (int off = 1; off < 16; off <<= 1) {
            vel += __shfl_xor(vel, off);
            ver += __shfl_xor(ver, off);
        }
        if (d == 0) {
            el2[node2 * 4 + ng] = vel;
            er2[node2 * 4 + ng] = ver;
        }
    }
}

// ---------------------------------------------------------------------------
// layer-2 aggregation (2 nodes/wave): head-mean (+b2) then 16-dim log-softmax.
// el2/er2 are compact [N,4] arrays.
// ---------------------------------------------------------------------------
__global__ __launch_bounds__(256) void agg_final_kernel(
    const int* __restrict__ cnt16, const unsigned short* __restrict__ col,
    const float* __restrict__ el2, const float* __restrict__ er2,
    const unsigned int* __restrict__ Hf32, const float* __restrict__ b,
    float* __restrict__ out, int n)
{
    const int lane = threadIdx.x & 63;
    const int wave = threadIdx.x >> 6;
    const int hl = lane & 31;
    const int hb = lane & 32;
    const int node = blockIdx.x * 8 + wave * 2 + (lane >> 5);
    if (node >= n) return;
    const int hd = hl >> 3;
    const int cg = hd * 16 + (hl & 7) * 2;
    const float erv_a = er2[node * 4 + (hl & 3)];
    const float bL = b[cg];
    const float bH = b[cg + 1];
    const int len = min(cnt16[(unsigned)node * 16], CAP);
    const int len_max = max(len, __shfl_xor(len, 32));
    float accL, accH, sacc_a;
    agg_walk_pair<4>(col + (unsigned)node * CAP, len, len_max, el2, Hf32,
                     hb, hl, erv_a, accL, accH, sacc_a);
    const float sc = __shfl(sacc_a, hb + hd);
    float zL = sc > 0.f ? accL / sc : 0.f;
    float zH = sc > 0.f ? accH / sc : 0.f;
    zL += bL;   zH += bH;
    zL += __shfl_xor(zL, 8);  zL += __shfl_xor(zL, 16);  zL *= 0.25f;
    zH += __shfl_xor(zH, 8);  zH += __shfl_xor(zH, 16);  zH *= 0.25f;
    float m = fmaxf(zL, zH);
    m = fmaxf(m, __shfl_xor(m, 1));
    m = fmaxf(m, __shfl_xor(m, 2));
    m = fmaxf(m, __shfl_xor(m, 4));
    float se = __expf(zL - m) + __expf(zH - m);
    se += __shfl_xor(se, 1);
    se += __shfl_xor(se, 2);
    se += __shfl_xor(se, 4);
    const float lse = __logf(se);
    if (hl < 8) {
        v2f r;
        r[0] = zL - m - lse;
        r[1] = zH - m - lse;
        __builtin_nontemporal_store(r, (v2f*)(out + (size_t)node * 16 + hl * 2));
    }
}

extern "C" void kernel_launch(void* const* d_in, const int* in_sizes, int n_in,
                              void* d_out, int out_size, void* d_ws, size_t ws_size,
                              hipStream_t stream)
{
    const float* feat = (const float*)d_in[0];
    const int*   src  = (const int*)d_in[1];
    const int*   dst  = (const int*)d_in[2];
    const float* W1   = (const float*)d_in[3];
    const float* al1  = (const float*)d_in[4];
    const float* ar1  = (const float*)d_in[5];
    const float* b1   = (const float*)d_in[6];
    const float* W2   = (const float*)d_in[7];
    const float* al2  = (const float*)d_in[8];
    const float* ar2  = (const float*)d_in[9];
    const float* b2   = (const float*)d_in[10];
    float* out = (float*)d_out;

    float* el1 = (float*)d_ws;                                // [N,4]
    float* er1 = el1 + N_NODES * 4;                           // [N,4]
    float* el2 = er1 + N_NODES * 4;                           // [N,4] compact
    float* er2 = el2 + N_NODES * 4;                           // [N,4] compact
    int*   cnt16 = (int*)(er2 + N_NODES * 4);                 // [N*16] padded
    uintptr_t p = ((uintptr_t)(cnt16 + N_NODES * 16) + 15) & ~(uintptr_t)15;
    unsigned short* col = (unsigned short*)p;                 // [N*CAP + 64]
    unsigned short* A   = col + (size_t)N_NODES * CAP + 64;   // h1 [N,64] bf16
    unsigned short* B   = A + (size_t)N_NODES * 64;           // h2 [N,64] bf16

    const int AB2 = (N_NODES + 7) / 8;              // 6250 agg blocks

    // ---- bucket-CSR zeroing (cnt16 rows + col incl. tail) ----
    (void)hipMemsetAsync(cnt16, 0, (size_t)((char*)A - (char*)cnt16), stream);

    // ---- layer 1: fc1 MFMA overlapped with bucket scatter (independent) ----
    l1_fused_kernel<<<FC_BLOCKS + SCAT_BLOCKS, 256, 0, stream>>>(
        feat, W1, al1, ar1, A, el1, er1, src, dst, cnt16, col);

    // ---- agg1 + fc2 fused (h1 never leaves the block) ----
    agg1_fc2_fused<<<TILES, 512, 0, stream>>>(
        cnt16, col, el1, er1, (const unsigned int*)A, b1,
        W2, al2, ar2, B, el2, er2);

    // ---- layer 2 aggregation + log-softmax ----
    agg_final_kernel<<<AB2, 256, 0, stream>>>(cnt16, col, el2, er2,
                                              (const unsigned int*)B, b2,
                                              out, N_NODES);
}